// Round 2
// baseline (1598.574 us; speedup 1.0000x reference)
//
#include <hip/hip_runtime.h>
#include <hip/hip_bf16.h>
#include <stdint.h>

#define B 8
#define N 4096
#define C 1024
#define H 16
#define D 64
// SCALE = D^-0.5 = 0.125

static __device__ __forceinline__ float bf_lo(uint32_t u) {
    union { uint32_t i; float f; } c; c.i = u << 16; return c.f;
}
static __device__ __forceinline__ float bf_hi(uint32_t u) {
    union { uint32_t i; float f; } c; c.i = u & 0xffff0000u; return c.f;
}

// Kernel A: one wave per W row r (0..2C); computes k[b,*,r] (r<C) or v (r>=C)
// for ALL 8 batches -> W read exactly once. emb (32 KB) stays L2-hot.
__global__ __launch_bounds__(256, 2)
void kv_kernel(const float* __restrict__ emb,
               const float* __restrict__ Wk,
               const float* __restrict__ Wv,
               float* __restrict__ kbuf,
               float* __restrict__ vbuf) {
    int wave = (blockIdx.x * blockDim.x + threadIdx.x) >> 6;  // 0..2047
    int lane = threadIdx.x & 63;
    int r = wave;
    const float* Wrow = (r < C) ? (Wk + (size_t)r * C) : (Wv + (size_t)(r - C) * C);
    float4 w4[4];
#pragma unroll
    for (int j = 0; j < 4; ++j) w4[j] = *(const float4*)(Wrow + (lane + 64 * j) * 4);
    float acc[B];
#pragma unroll
    for (int b = 0; b < B; ++b) {
        const float* e = emb + (size_t)b * C;
        float a = 0.f;
#pragma unroll
        for (int j = 0; j < 4; ++j) {
            float4 e4 = *(const float4*)(e + (lane + 64 * j) * 4);
            a += w4[j].x * e4.x + w4[j].y * e4.y + w4[j].z * e4.z + w4[j].w * e4.w;
        }
        acc[b] = a;
    }
#pragma unroll
    for (int off = 32; off; off >>= 1)
#pragma unroll
        for (int b = 0; b < B; ++b) acc[b] += __shfl_xor(acc[b], off, 64);
    if (lane == 0) {
        float* dst = (r < C) ? (kbuf + r) : (vbuf + (r - C));
#pragma unroll
        for (int b = 0; b < B; ++b) dst[b * C] = acc[b];
    }
}

// Kernel B: fold weights. block = (b,h,which).
//   which==0: w[b,h,c]  = sum_d Wq[(hD+d)*C + c] * k[b,h,d]   (bf16 out)
//   which==1: U[b,h,c'] = sum_d Wp[c'*C + hD + d] * v[b,h,d]  (bf16 out)
__global__ __launch_bounds__(256, 2)
void wu_kernel(const float* __restrict__ Wq,
               const float* __restrict__ Wp,
               const float* __restrict__ kbuf,
               const float* __restrict__ vbuf,
               __hip_bfloat16* __restrict__ wbuf,
               __hip_bfloat16* __restrict__ ubuf) {
    int id = blockIdx.x;
    int which = id & 1; id >>= 1;
    int h = id % H;
    int b = id / H;
    int t = threadIdx.x;
    if (which == 0) {
        const float* kk = kbuf + (size_t)(b * H + h) * D;
        int c = t * 4;
        float4 acc = {0.f, 0.f, 0.f, 0.f};
#pragma unroll 8
        for (int d = 0; d < D; ++d) {
            float kvs = kk[d];
            float4 w4 = *(const float4*)(Wq + (size_t)(h * D + d) * C + c);
            acc.x += kvs * w4.x; acc.y += kvs * w4.y;
            acc.z += kvs * w4.z; acc.w += kvs * w4.w;
        }
        __hip_bfloat16* o = wbuf + (size_t)(b * H + h) * C + c;
        o[0] = __float2bfloat16(acc.x); o[1] = __float2bfloat16(acc.y);
        o[2] = __float2bfloat16(acc.z); o[3] = __float2bfloat16(acc.w);
    } else {
        // 4 lanes per output row c'; lane-in-group q covers d = q*16 + 0..15.
        const int q = t & 3;
        const float* vv = vbuf + (size_t)(b * H + h) * D + q * 16;
        float4 v4[4];
#pragma unroll
        for (int m = 0; m < 4; ++m) v4[m] = *(const float4*)(vv + m * 4);
#pragma unroll
        for (int p = 0; p < 16; ++p) {
            int cp = p * 64 + (t >> 2);
            const float* wp = Wp + (size_t)cp * C + h * D + q * 16;
            float acc = 0.f;
#pragma unroll
            for (int m = 0; m < 4; ++m) {
                float4 w4 = *(const float4*)(wp + m * 4);
                acc += w4.x * v4[m].x + w4.y * v4[m].y
                     + w4.z * v4[m].z + w4.w * v4[m].w;
            }
            acc += __shfl_xor(acc, 1, 64);
            acc += __shfl_xor(acc, 2, 64);
            if (q == 0) ubuf[(size_t)(b * H + h) * C + cp] = __float2bfloat16(acc);
        }
    }
}

// Kernel C: fused main pass, 4 ROWS PER ITERATION.
// One wave per 16 rows, processed as 4 groups of 4 rows. Each sweep over the
// staged weights (w_s for logits, u_s for the epilogue) now serves 4 rows:
// each weight word is read once, unpacked once, FMA'd against 4 rows.
// -> per-row weight-read traffic and DS ops cut 4x, unpack VALU cut ~4x.
// grid = (64, B), block = 256 (4 waves). LDS = 64KB -> 2 blocks/CU.
// Numerics: identical per-row accumulation order, butterfly offsets, and
// epilogue order as before.
__global__ __launch_bounds__(256, 2)
void main_kernel(const float* __restrict__ fea,
                 const __hip_bfloat16* __restrict__ wbuf,
                 const __hip_bfloat16* __restrict__ ubuf,
                 const float* __restrict__ bp,
                 float* __restrict__ out) {
    __shared__ uint32_t w_s[H * C / 2];  // bf16x2 packed, 32 KB
    __shared__ uint32_t u_s[H * C / 2];  // 32 KB
    const int b = blockIdx.y;
    const int tile = blockIdx.x;
    const int tid = threadIdx.x;

    {
        const uint4* wsrc = (const uint4*)(wbuf + (size_t)b * H * C);
        const uint4* usrc = (const uint4*)(ubuf + (size_t)b * H * C);
        uint4* wdst = (uint4*)w_s;
        uint4* udst = (uint4*)u_s;
#pragma unroll
        for (int i = 0; i < H * C / 8 / 256; ++i) {
            wdst[tid + i * 256] = wsrc[tid + i * 256];
            udst[tid + i * 256] = usrc[tid + i * 256];
        }
    }
    __syncthreads();

    const int lane = tid & 63;
    const int wv = tid >> 6;          // 0..3
    const int row0 = tile * 64 + wv * 16;

    float4 bp4[4];
#pragma unroll
    for (int j = 0; j < 4; ++j) bp4[j] = *(const float4*)(bp + 4 * lane + 256 * j);

#pragma unroll 1
    for (int g = 0; g < 4; ++g) {
        const float* fr = fea + ((size_t)b * N + row0 + 4 * g) * C + 4 * lane;

        // Load 4 rows' fea slices (16 x dwordx4).
        float4 f[4][4];
#pragma unroll
        for (int r = 0; r < 4; ++r)
#pragma unroll
            for (int j = 0; j < 4; ++j)
                f[r][j] = *(const float4*)(fr + (size_t)r * C + 256 * j);

        // Logit partials for 4 rows x 16 heads. One sweep over w_s serves
        // all 4 rows: unpack each bf16x2 word once, 4 FMAs per float.
        float s[4][H];
#pragma unroll
        for (int h = 0; h < H; ++h) {
            const uint32_t* wrow = w_s + h * (C / 2) + 2 * lane;
#pragma unroll
            for (int r = 0; r < 4; ++r) s[r][h] = 0.f;
#pragma unroll
            for (int j = 0; j < 4; ++j) {
                uint2 p = *(const uint2*)(wrow + 128 * j);
                float lx = bf_lo(p.x), hx = bf_hi(p.x);
                float ly = bf_lo(p.y), hy = bf_hi(p.y);
#pragma unroll
                for (int r = 0; r < 4; ++r)
                    s[r][h] += f[r][j].x * lx + f[r][j].y * hx
                             + f[r][j].z * ly + f[r][j].w * hy;
            }
        }

        // Packed butterfly: 6 steps x 64 independent values.
#pragma unroll
        for (int off = 32; off; off >>= 1)
#pragma unroll
            for (int r = 0; r < 4; ++r)
#pragma unroll
                for (int h = 0; h < H; ++h)
                    s[r][h] += __shfl_xor(s[r][h], off, 64);

        // Uniform sigmoid (identical on all lanes).
#pragma unroll
        for (int r = 0; r < 4; ++r)
#pragma unroll
            for (int h = 0; h < H; ++h)
                s[r][h] = 1.f / (1.f + __expf(-0.125f * s[r][h]));

        // Epilogue: one sweep over u_s serves 4 rows.
        float* orow = out + ((size_t)b * N + row0 + 4 * g) * C + 4 * lane;
#pragma unroll
        for (int j = 0; j < 4; ++j) {
            float4 acc[4];
#pragma unroll
            for (int r = 0; r < 4; ++r) {
                acc[r] = f[r][j];
                acc[r].x += bp4[j].x; acc[r].y += bp4[j].y;
                acc[r].z += bp4[j].z; acc[r].w += bp4[j].w;
            }
            const uint32_t* urow = u_s + 2 * lane + 128 * j;
#pragma unroll
            for (int h = 0; h < H; ++h) {
                uint2 p = *(const uint2*)(urow + h * (C / 2));
                float lx = bf_lo(p.x), hx = bf_hi(p.x);
                float ly = bf_lo(p.y), hy = bf_hi(p.y);
#pragma unroll
                for (int r = 0; r < 4; ++r) {
                    acc[r].x += s[r][h] * lx; acc[r].y += s[r][h] * hx;
                    acc[r].z += s[r][h] * ly; acc[r].w += s[r][h] * hy;
                }
            }
#pragma unroll
            for (int r = 0; r < 4; ++r)
                *(float4*)(orow + (size_t)r * C + 256 * j) = acc[r];
        }
    }
}

extern "C" void kernel_launch(void* const* d_in, const int* in_sizes, int n_in,
                              void* d_out, int out_size, void* d_ws, size_t ws_size,
                              hipStream_t stream) {
    const float* fea = (const float*)d_in[0];
    const float* emb = (const float*)d_in[1];
    const float* Wq  = (const float*)d_in[2];
    const float* Wk  = (const float*)d_in[3];
    const float* Wv  = (const float*)d_in[4];
    const float* Wp  = (const float*)d_in[5];
    const float* bp  = (const float*)d_in[6];
    float* out = (float*)d_out;

    char* ws = (char*)d_ws;
    float* kbuf = (float*)ws;                                  // B*C f32 = 32KB
    float* vbuf = (float*)(ws + 32 * 1024);                    // 32KB
    __hip_bfloat16* wbuf = (__hip_bfloat16*)(ws + 64 * 1024);  // B*H*C bf16 = 256KB
    __hip_bfloat16* ubuf = (__hip_bfloat16*)(ws + 320 * 1024); // 256KB

    hipLaunchKernelGGL(kv_kernel, dim3(2 * C / 4), dim3(256), 0, stream,
                       emb, Wk, Wv, kbuf, vbuf);
    hipLaunchKernelGGL(wu_kernel, dim3(B * H * 2), dim3(256), 0, stream,
                       Wq, Wp, kbuf, vbuf, wbuf, ubuf);
    hipLaunchKernelGGL(main_kernel, dim3(N / 64, B), dim3(256), 0, stream,
                       fea, wbuf, ubuf, bp, out);
}

// Round 3
// 321.129 us; speedup vs baseline: 4.9780x; 4.9780x over previous
//
#include <hip/hip_runtime.h>
#include <hip/hip_bf16.h>
#include <stdint.h>

#define B 8
#define N 4096
#define C 1024
#define H 16
#define D 64
// SCALE = D^-0.5 = 0.125

static __device__ __forceinline__ float bf_lo(uint32_t u) {
    union { uint32_t i; float f; } c; c.i = u << 16; return c.f;
}
static __device__ __forceinline__ float bf_hi(uint32_t u) {
    union { uint32_t i; float f; } c; c.i = u & 0xffff0000u; return c.f;
}

// Kernel A: one wave per W row r (0..2C); computes k[b,*,r] (r<C) or v (r>=C)
// for ALL 8 batches -> W read exactly once. emb (32 KB) stays L2-hot.
__global__ __launch_bounds__(256, 2)
void kv_kernel(const float* __restrict__ emb,
               const float* __restrict__ Wk,
               const float* __restrict__ Wv,
               float* __restrict__ kbuf,
               float* __restrict__ vbuf) {
    int wave = (blockIdx.x * blockDim.x + threadIdx.x) >> 6;  // 0..2047
    int lane = threadIdx.x & 63;
    int r = wave;
    const float* Wrow = (r < C) ? (Wk + (size_t)r * C) : (Wv + (size_t)(r - C) * C);
    float4 w4[4];
#pragma unroll
    for (int j = 0; j < 4; ++j) w4[j] = *(const float4*)(Wrow + (lane + 64 * j) * 4);
    float acc[B];
#pragma unroll
    for (int b = 0; b < B; ++b) {
        const float* e = emb + (size_t)b * C;
        float a = 0.f;
#pragma unroll
        for (int j = 0; j < 4; ++j) {
            float4 e4 = *(const float4*)(e + (lane + 64 * j) * 4);
            a += w4[j].x * e4.x + w4[j].y * e4.y + w4[j].z * e4.z + w4[j].w * e4.w;
        }
        acc[b] = a;
    }
#pragma unroll
    for (int off = 32; off; off >>= 1)
#pragma unroll
        for (int b = 0; b < B; ++b) acc[b] += __shfl_xor(acc[b], off, 64);
    if (lane == 0) {
        float* dst = (r < C) ? (kbuf + r) : (vbuf + (r - C));
#pragma unroll
        for (int b = 0; b < B; ++b) dst[b * C] = acc[b];
    }
}

// Kernel B: fold weights. block = (b,h,which).
//   which==0: w[b,h,c]  = sum_d Wq[(hD+d)*C + c] * k[b,h,d]   (bf16 out)
//   which==1: U[b,h,c'] = sum_d Wp[c'*C + hD + d] * v[b,h,d]  (bf16 out)
__global__ __launch_bounds__(256, 2)
void wu_kernel(const float* __restrict__ Wq,
               const float* __restrict__ Wp,
               const float* __restrict__ kbuf,
               const float* __restrict__ vbuf,
               __hip_bfloat16* __restrict__ wbuf,
               __hip_bfloat16* __restrict__ ubuf) {
    int id = blockIdx.x;
    int which = id & 1; id >>= 1;
    int h = id % H;
    int b = id / H;
    int t = threadIdx.x;
    if (which == 0) {
        const float* kk = kbuf + (size_t)(b * H + h) * D;
        int c = t * 4;
        float4 acc = {0.f, 0.f, 0.f, 0.f};
#pragma unroll 8
        for (int d = 0; d < D; ++d) {
            float kvs = kk[d];
            float4 w4 = *(const float4*)(Wq + (size_t)(h * D + d) * C + c);
            acc.x += kvs * w4.x; acc.y += kvs * w4.y;
            acc.z += kvs * w4.z; acc.w += kvs * w4.w;
        }
        __hip_bfloat16* o = wbuf + (size_t)(b * H + h) * C + c;
        o[0] = __float2bfloat16(acc.x); o[1] = __float2bfloat16(acc.y);
        o[2] = __float2bfloat16(acc.z); o[3] = __float2bfloat16(acc.w);
    } else {
        // 4 lanes per output row c'; lane-in-group q covers d = q*16 + 0..15.
        const int q = t & 3;
        const float* vv = vbuf + (size_t)(b * H + h) * D + q * 16;
        float4 v4[4];
#pragma unroll
        for (int m = 0; m < 4; ++m) v4[m] = *(const float4*)(vv + m * 4);
#pragma unroll
        for (int p = 0; p < 16; ++p) {
            int cp = p * 64 + (t >> 2);
            const float* wp = Wp + (size_t)cp * C + h * D + q * 16;
            float acc = 0.f;
#pragma unroll
            for (int m = 0; m < 4; ++m) {
                float4 w4 = *(const float4*)(wp + m * 4);
                acc += w4.x * v4[m].x + w4.y * v4[m].y
                     + w4.z * v4[m].z + w4.w * v4[m].w;
            }
            acc += __shfl_xor(acc, 1, 64);
            acc += __shfl_xor(acc, 2, 64);
            if (q == 0) ubuf[(size_t)(b * H + h) * C + cp] = __float2bfloat16(acc);
        }
    }
}

// Kernel C: fused main pass — SMALL-CODE version.
// Theory: previous versions fully unrolled the 16-head logit sweep and the
// 16-head epilogue -> ~1800-instruction (~14-28 KB) row bodies that thrash
// the 32 KB L1I; 8 drifting waves/CU re-stream the body from L2 every row
// (~200 cy / 64B line) -> the observed ~97% stall, invariant to compute
// structure and occupancy.
// Fix: ONE rolled head-loop per row. Per head: read w slice (4x ds_read_b64),
// dot, full 6-step butterfly (all lanes end with the identical sum),
// uniform sigmoid, then immediately accumulate that head's u-contribution
// into the 4 float4 output accumulators. Static row body ~130 instructions
// (~1 KB); whole kernel fits L1I permanently.
// No register array is runtime-indexed (f[j]/acc[j] j-loops are unrolled,
// s is scalar; the head index only forms LDS addresses) -> no scratch.
// Accumulation order (dot order, butterfly offsets, h-ascending epilogue)
// is bit-identical to the previous version -> absmax unchanged.
__global__ __launch_bounds__(256, 2)
void main_kernel(const float* __restrict__ fea,
                 const __hip_bfloat16* __restrict__ wbuf,
                 const __hip_bfloat16* __restrict__ ubuf,
                 const float* __restrict__ bp,
                 float* __restrict__ out) {
    __shared__ uint32_t w_s[H * C / 2];  // bf16x2 packed, 32 KB
    __shared__ uint32_t u_s[H * C / 2];  // 32 KB
    const int b = blockIdx.y;
    const int tile = blockIdx.x;
    const int tid = threadIdx.x;

    {
        const uint4* wsrc = (const uint4*)(wbuf + (size_t)b * H * C);
        const uint4* usrc = (const uint4*)(ubuf + (size_t)b * H * C);
        uint4* wdst = (uint4*)w_s;
        uint4* udst = (uint4*)u_s;
#pragma unroll
        for (int i = 0; i < H * C / 8 / 256; ++i) {
            wdst[tid + i * 256] = wsrc[tid + i * 256];
            udst[tid + i * 256] = usrc[tid + i * 256];
        }
    }
    __syncthreads();

    const int lane = tid & 63;
    const int wv = tid >> 6;          // 0..3
    const int row0 = tile * 64 + wv * 16;

    float4 bp4[4];
#pragma unroll
    for (int j = 0; j < 4; ++j) bp4[j] = *(const float4*)(bp + 4 * lane + 256 * j);

#pragma unroll 1
    for (int i = 0; i < 16; ++i) {
        const float* fr = fea + ((size_t)b * N + row0 + i) * C + 4 * lane;
        float4 f[4];
#pragma unroll
        for (int j = 0; j < 4; ++j) f[j] = *(const float4*)(fr + 256 * j);

        // Output accumulators start at fea + bias (residual + bp).
        float4 acc[4];
#pragma unroll
        for (int j = 0; j < 4; ++j) {
            acc[j].x = f[j].x + bp4[j].x; acc[j].y = f[j].y + bp4[j].y;
            acc[j].z = f[j].z + bp4[j].z; acc[j].w = f[j].w + bp4[j].w;
        }

        // One rolled loop over heads: logit -> butterfly -> sigmoid -> apply.
#pragma unroll 1
        for (int h = 0; h < H; ++h) {
            const uint32_t* wrow = w_s + h * (C / 2) + 2 * lane;
            float s = 0.f;
#pragma unroll
            for (int j = 0; j < 4; ++j) {
                uint2 p = *(const uint2*)(wrow + 128 * j);
                s += f[j].x * bf_lo(p.x) + f[j].y * bf_hi(p.x)
                   + f[j].z * bf_lo(p.y) + f[j].w * bf_hi(p.y);
            }
#pragma unroll
            for (int off = 32; off; off >>= 1) s += __shfl_xor(s, off, 64);
            // After the full butterfly every lane holds the identical sum.
            float sig = 1.f / (1.f + __expf(-0.125f * s));

            const uint32_t* urow = u_s + h * (C / 2) + 2 * lane;
#pragma unroll
            for (int j = 0; j < 4; ++j) {
                uint2 p = *(const uint2*)(urow + 128 * j);
                acc[j].x += sig * bf_lo(p.x); acc[j].y += sig * bf_hi(p.x);
                acc[j].z += sig * bf_lo(p.y); acc[j].w += sig * bf_hi(p.y);
            }
        }

        float* op = out + ((size_t)b * N + row0 + i) * C + 4 * lane;
#pragma unroll
        for (int j = 0; j < 4; ++j) *(float4*)(op + 256 * j) = acc[j];
    }
}

extern "C" void kernel_launch(void* const* d_in, const int* in_sizes, int n_in,
                              void* d_out, int out_size, void* d_ws, size_t ws_size,
                              hipStream_t stream) {
    const float* fea = (const float*)d_in[0];
    const float* emb = (const float*)d_in[1];
    const float* Wq  = (const float*)d_in[2];
    const float* Wk  = (const float*)d_in[3];
    const float* Wv  = (const float*)d_in[4];
    const float* Wp  = (const float*)d_in[5];
    const float* bp  = (const float*)d_in[6];
    float* out = (float*)d_out;

    char* ws = (char*)d_ws;
    float* kbuf = (float*)ws;                                  // B*C f32 = 32KB
    float* vbuf = (float*)(ws + 32 * 1024);                    // 32KB
    __hip_bfloat16* wbuf = (__hip_bfloat16*)(ws + 64 * 1024);  // B*H*C bf16 = 256KB
    __hip_bfloat16* ubuf = (__hip_bfloat16*)(ws + 320 * 1024); // 256KB

    hipLaunchKernelGGL(kv_kernel, dim3(2 * C / 4), dim3(256), 0, stream,
                       emb, Wk, Wv, kbuf, vbuf);
    hipLaunchKernelGGL(wu_kernel, dim3(B * H * 2), dim3(256), 0, stream,
                       Wq, Wp, kbuf, vbuf, wbuf, ubuf);
    hipLaunchKernelGGL(main_kernel, dim3(N / 64, B), dim3(256), 0, stream,
                       fea, wbuf, ubuf, bp, out);
}

// Round 4
// 290.978 us; speedup vs baseline: 5.4938x; 1.1036x over previous
//
#include <hip/hip_runtime.h>
#include <hip/hip_bf16.h>
#include <stdint.h>

#define B 8
#define N 4096
#define C 1024
#define H 16
#define D 64
// SCALE = D^-0.5 = 0.125

static __device__ __forceinline__ float bf_lo(uint32_t u) {
    union { uint32_t i; float f; } c; c.i = u << 16; return c.f;
}
static __device__ __forceinline__ float bf_hi(uint32_t u) {
    union { uint32_t i; float f; } c; c.i = u & 0xffff0000u; return c.f;
}

// Kernel A: one wave per W row r (0..2C); computes k[b,*,r] (r<C) or v (r>=C)
// for ALL 8 batches -> W read exactly once. emb (32 KB) stays L2-hot.
__global__ __launch_bounds__(256, 2)
void kv_kernel(const float* __restrict__ emb,
               const float* __restrict__ Wk,
               const float* __restrict__ Wv,
               float* __restrict__ kbuf,
               float* __restrict__ vbuf) {
    int wave = (blockIdx.x * blockDim.x + threadIdx.x) >> 6;  // 0..2047
    int lane = threadIdx.x & 63;
    int r = wave;
    const float* Wrow = (r < C) ? (Wk + (size_t)r * C) : (Wv + (size_t)(r - C) * C);
    float4 w4[4];
#pragma unroll
    for (int j = 0; j < 4; ++j) w4[j] = *(const float4*)(Wrow + (lane + 64 * j) * 4);
    float acc[B];
#pragma unroll
    for (int b = 0; b < B; ++b) {
        const float* e = emb + (size_t)b * C;
        float a = 0.f;
#pragma unroll
        for (int j = 0; j < 4; ++j) {
            float4 e4 = *(const float4*)(e + (lane + 64 * j) * 4);
            a += w4[j].x * e4.x + w4[j].y * e4.y + w4[j].z * e4.z + w4[j].w * e4.w;
        }
        acc[b] = a;
    }
#pragma unroll
    for (int off = 32; off; off >>= 1)
#pragma unroll
        for (int b = 0; b < B; ++b) acc[b] += __shfl_xor(acc[b], off, 64);
    if (lane == 0) {
        float* dst = (r < C) ? (kbuf + r) : (vbuf + (r - C));
#pragma unroll
        for (int b = 0; b < B; ++b) dst[b * C] = acc[b];
    }
}

// Kernel B (rewritten): fold weights with the BATCH LOOP INNERMOST so each
// Wq/Wp element is read exactly ONCE (8 MB total vs 64 MB before) and feeds
// 8 FMAs. 128 blocks x 256 threads.
//   id <  64: w[b,h,c]  = sum_d Wq[(hD+d)*C + c] * k[b,h,d]   (d ascending,
//             same order as before -> wbuf bit-identical)
//   id >= 64: U[b,h,c'] = sum_d Wp[c'*C + hD + d] * v[b,h,d]  computed as the
//             exact 4-chunk reduction tree of the old kernel:
//             (c0+c1)+(c2+c3), chunk q = d in [16q,16q+16) m-ascending
//             -> ubuf bit-identical.
__global__ __launch_bounds__(256)
void wu_kernel(const float* __restrict__ Wq,
               const float* __restrict__ Wp,
               const float* __restrict__ kbuf,
               const float* __restrict__ vbuf,
               __hip_bfloat16* __restrict__ wbuf,
               __hip_bfloat16* __restrict__ ubuf) {
    int id = blockIdx.x;
    int t = threadIdx.x;
    if (id < 64) {
        int h = id >> 2;
        int c = ((id & 3) << 8) + t;
        const float* kk = kbuf + h * D;  // k[b][hD+d] at kk[b*C + d]
        float acc[B];
#pragma unroll
        for (int b = 0; b < B; ++b) acc[b] = 0.f;
#pragma unroll 4
        for (int d = 0; d < D; ++d) {
            float wv = Wq[(size_t)(h * D + d) * C + c];
#pragma unroll
            for (int b = 0; b < B; ++b) acc[b] += kk[(size_t)b * C + d] * wv;
        }
#pragma unroll
        for (int b = 0; b < B; ++b)
            wbuf[(size_t)(b * H + h) * C + c] = __float2bfloat16(acc[b]);
    } else {
        int id2 = id - 64;
        int h = id2 >> 2;
        int cp = ((id2 & 3) << 8) + t;
        const float* vv = vbuf + h * D;  // v[b][hD+d] at vv[b*C + d]
        float aq[4][B];
#pragma unroll
        for (int q = 0; q < 4; ++q)
#pragma unroll
            for (int b = 0; b < B; ++b) aq[q][b] = 0.f;
#pragma unroll
        for (int q = 0; q < 4; ++q) {
#pragma unroll
            for (int m = 0; m < 4; ++m) {
                int d0 = q * 16 + m * 4;
                float4 w4 = *(const float4*)(Wp + (size_t)cp * C + h * D + d0);
#pragma unroll
                for (int b = 0; b < B; ++b) {
                    const float* vb = vv + (size_t)b * C + d0;
                    aq[q][b] += w4.x * vb[0] + w4.y * vb[1]
                              + w4.z * vb[2] + w4.w * vb[3];
                }
            }
        }
#pragma unroll
        for (int b = 0; b < B; ++b)
            ubuf[(size_t)(b * H + h) * C + cp] =
                __float2bfloat16((aq[0][b] + aq[1][b]) + (aq[2][b] + aq[3][b]));
    }
}

// Kernel C: fused main pass — small-code + f32-LDS + 2-rows-per-sweep.
// One 512-thread block per CU (grid 32x8 = 256 = CU count), 128 KB LDS
// (w,u unpacked to f32 at staging -> zero unpack VALU in the hot loop),
// 8 waves/CU (same occupancy as the 64KB/2-block version).
// Per wave: 16 rows as 8 groups of 2; each head-sweep over the f32 weights
// serves 2 rows (halves LDS-read cycles and shuffles per row).
// Head loop stays ROLLED (~100 instr body) — R3 proved code size was the
// 9x stall; R2's 4-row variant failed on spills+code size, both fixed here
// (2 rows, statically-indexed register arrays only).
// Numerics bit-identical: same element order (f32 LDS holds exactly the
// unpacked bf16 values), same dot/butterfly/epilogue order.
__global__ __launch_bounds__(512)
void main_kernel(const float* __restrict__ fea,
                 const __hip_bfloat16* __restrict__ wbuf,
                 const __hip_bfloat16* __restrict__ ubuf,
                 const float* __restrict__ bp,
                 float* __restrict__ out) {
    __shared__ float w_f[H * C];  // 64 KB
    __shared__ float u_f[H * C];  // 64 KB
    const int b = blockIdx.y;
    const int tile = blockIdx.x;
    const int tid = threadIdx.x;

    {
        const uint32_t* wsrc = (const uint32_t*)(wbuf + (size_t)b * H * C);
        const uint32_t* usrc = (const uint32_t*)(ubuf + (size_t)b * H * C);
#pragma unroll
        for (int i = 0; i < H * C / 2 / 512; ++i) {  // 16 iters
            int wi = tid + i * 512;
            uint32_t pw = wsrc[wi];
            uint32_t pu = usrc[wi];
            *(float2*)(w_f + 2 * wi) = make_float2(bf_lo(pw), bf_hi(pw));
            *(float2*)(u_f + 2 * wi) = make_float2(bf_lo(pu), bf_hi(pu));
        }
    }
    __syncthreads();

    const int lane = tid & 63;
    const int wv = tid >> 6;          // 0..7
    const int row0 = tile * 128 + wv * 16;

    float4 bp4[4];
#pragma unroll
    for (int j = 0; j < 4; ++j) bp4[j] = *(const float4*)(bp + 4 * lane + 256 * j);

    const float* fbase = fea + ((size_t)b * N + row0) * C + 4 * lane;
    float* obase = out + ((size_t)b * N + row0) * C + 4 * lane;

    // Group 0 rows.
    float4 fa[2][4];
#pragma unroll
    for (int r = 0; r < 2; ++r)
#pragma unroll
        for (int j = 0; j < 4; ++j)
            fa[r][j] = *(const float4*)(fbase + (size_t)r * C + 256 * j);

#pragma unroll 1
    for (int g = 0; g < 8; ++g) {
        // Prefetch next group (clamped; uniform, branch-free).
        const int gp = (g < 7) ? g + 1 : g;
        float4 fb[2][4];
#pragma unroll
        for (int r = 0; r < 2; ++r)
#pragma unroll
            for (int j = 0; j < 4; ++j)
                fb[r][j] = *(const float4*)(fbase + (size_t)(2 * gp + r) * C + 256 * j);

        float4 acc[2][4];
#pragma unroll
        for (int r = 0; r < 2; ++r)
#pragma unroll
            for (int j = 0; j < 4; ++j) {
                acc[r][j].x = fa[r][j].x + bp4[j].x;
                acc[r][j].y = fa[r][j].y + bp4[j].y;
                acc[r][j].z = fa[r][j].z + bp4[j].z;
                acc[r][j].w = fa[r][j].w + bp4[j].w;
            }

#pragma unroll 1
        for (int h = 0; h < H; ++h) {
            const float* wrow = w_f + h * C + 4 * lane;
            float s[2];
            s[0] = 0.f; s[1] = 0.f;
#pragma unroll
            for (int j = 0; j < 4; ++j) {
                float4 w4 = *(const float4*)(wrow + 256 * j);
#pragma unroll
                for (int r = 0; r < 2; ++r)
                    s[r] += fa[r][j].x * w4.x + fa[r][j].y * w4.y
                          + fa[r][j].z * w4.z + fa[r][j].w * w4.w;
            }
#pragma unroll
            for (int off = 32; off; off >>= 1)
#pragma unroll
                for (int r = 0; r < 2; ++r) s[r] += __shfl_xor(s[r], off, 64);
#pragma unroll
            for (int r = 0; r < 2; ++r)
                s[r] = 1.f / (1.f + __expf(-0.125f * s[r]));

            const float* urow = u_f + h * C + 4 * lane;
#pragma unroll
            for (int j = 0; j < 4; ++j) {
                float4 u4 = *(const float4*)(urow + 256 * j);
#pragma unroll
                for (int r = 0; r < 2; ++r) {
                    acc[r][j].x += s[r] * u4.x; acc[r][j].y += s[r] * u4.y;
                    acc[r][j].z += s[r] * u4.z; acc[r][j].w += s[r] * u4.w;
                }
            }
        }

#pragma unroll
        for (int r = 0; r < 2; ++r)
#pragma unroll
            for (int j = 0; j < 4; ++j)
                *(float4*)(obase + (size_t)(2 * g + r) * C + 256 * j) = acc[r][j];

#pragma unroll
        for (int r = 0; r < 2; ++r)
#pragma unroll
            for (int j = 0; j < 4; ++j) fa[r][j] = fb[r][j];
    }
}

extern "C" void kernel_launch(void* const* d_in, const int* in_sizes, int n_in,
                              void* d_out, int out_size, void* d_ws, size_t ws_size,
                              hipStream_t stream) {
    const float* fea = (const float*)d_in[0];
    const float* emb = (const float*)d_in[1];
    const float* Wq  = (const float*)d_in[2];
    const float* Wk  = (const float*)d_in[3];
    const float* Wv  = (const float*)d_in[4];
    const float* Wp  = (const float*)d_in[5];
    const float* bp  = (const float*)d_in[6];
    float* out = (float*)d_out;

    char* ws = (char*)d_ws;
    float* kbuf = (float*)ws;                                  // B*C f32 = 32KB
    float* vbuf = (float*)(ws + 32 * 1024);                    // 32KB
    __hip_bfloat16* wbuf = (__hip_bfloat16*)(ws + 64 * 1024);  // B*H*C bf16 = 256KB
    __hip_bfloat16* ubuf = (__hip_bfloat16*)(ws + 320 * 1024); // 256KB

    hipLaunchKernelGGL(kv_kernel, dim3(2 * C / 4), dim3(256), 0, stream,
                       emb, Wk, Wv, kbuf, vbuf);
    hipLaunchKernelGGL(wu_kernel, dim3(128), dim3(256), 0, stream,
                       Wq, Wp, kbuf, vbuf, wbuf, ubuf);
    hipLaunchKernelGGL(main_kernel, dim3(N / 128, B), dim3(512), 0, stream,
                       fea, wbuf, ubuf, bp, out);
}

// Round 5
// 286.087 us; speedup vs baseline: 5.5877x; 1.0171x over previous
//
#include <hip/hip_runtime.h>
#include <hip/hip_bf16.h>
#include <stdint.h>

#define B 8
#define N 4096
#define C 1024
#define H 16
#define D 64
// SCALE = D^-0.5 = 0.125

static __device__ __forceinline__ float bf_lo(uint32_t u) {
    union { uint32_t i; float f; } c; c.i = u << 16; return c.f;
}
static __device__ __forceinline__ float bf_hi(uint32_t u) {
    union { uint32_t i; float f; } c; c.i = u & 0xffff0000u; return c.f;
}

// Kernel A: one wave per W row r (0..2C); computes k[b,*,r] (r<C) or v (r>=C)
// for ALL 8 batches -> W read exactly once. emb (32 KB) stays L2-hot.
__global__ __launch_bounds__(256, 2)
void kv_kernel(const float* __restrict__ emb,
               const float* __restrict__ Wk,
               const float* __restrict__ Wv,
               float* __restrict__ kbuf,
               float* __restrict__ vbuf) {
    int wave = (blockIdx.x * blockDim.x + threadIdx.x) >> 6;  // 0..2047
    int lane = threadIdx.x & 63;
    int r = wave;
    const float* Wrow = (r < C) ? (Wk + (size_t)r * C) : (Wv + (size_t)(r - C) * C);
    float4 w4[4];
#pragma unroll
    for (int j = 0; j < 4; ++j) w4[j] = *(const float4*)(Wrow + (lane + 64 * j) * 4);
    float acc[B];
#pragma unroll
    for (int b = 0; b < B; ++b) {
        const float* e = emb + (size_t)b * C;
        float a = 0.f;
#pragma unroll
        for (int j = 0; j < 4; ++j) {
            float4 e4 = *(const float4*)(e + (lane + 64 * j) * 4);
            a += w4[j].x * e4.x + w4[j].y * e4.y + w4[j].z * e4.z + w4[j].w * e4.w;
        }
        acc[b] = a;
    }
#pragma unroll
    for (int off = 32; off; off >>= 1)
#pragma unroll
        for (int b = 0; b < B; ++b) acc[b] += __shfl_xor(acc[b], off, 64);
    if (lane == 0) {
        float* dst = (r < C) ? (kbuf + r) : (vbuf + (r - C));
#pragma unroll
        for (int b = 0; b < B; ++b) dst[b * C] = acc[b];
    }
}

// Kernel B: fold weights with the BATCH LOOP INNERMOST so each Wq/Wp element
// is read exactly ONCE (8 MB total) and feeds 8 FMAs. 128 blocks x 256 thr.
__global__ __launch_bounds__(256)
void wu_kernel(const float* __restrict__ Wq,
               const float* __restrict__ Wp,
               const float* __restrict__ kbuf,
               const float* __restrict__ vbuf,
               __hip_bfloat16* __restrict__ wbuf,
               __hip_bfloat16* __restrict__ ubuf) {
    int id = blockIdx.x;
    int t = threadIdx.x;
    if (id < 64) {
        int h = id >> 2;
        int c = ((id & 3) << 8) + t;
        const float* kk = kbuf + h * D;  // k[b][hD+d] at kk[b*C + d]
        float acc[B];
#pragma unroll
        for (int b = 0; b < B; ++b) acc[b] = 0.f;
#pragma unroll 4
        for (int d = 0; d < D; ++d) {
            float wv = Wq[(size_t)(h * D + d) * C + c];
#pragma unroll
            for (int b = 0; b < B; ++b) acc[b] += kk[(size_t)b * C + d] * wv;
        }
#pragma unroll
        for (int b = 0; b < B; ++b)
            wbuf[(size_t)(b * H + h) * C + c] = __float2bfloat16(acc[b]);
    } else {
        int id2 = id - 64;
        int h = id2 >> 2;
        int cp = ((id2 & 3) << 8) + t;
        const float* vv = vbuf + h * D;  // v[b][hD+d] at vv[b*C + d]
        float aq[4][B];
#pragma unroll
        for (int q = 0; q < 4; ++q)
#pragma unroll
            for (int b = 0; b < B; ++b) aq[q][b] = 0.f;
#pragma unroll
        for (int q = 0; q < 4; ++q) {
#pragma unroll
            for (int m = 0; m < 4; ++m) {
                int d0 = q * 16 + m * 4;
                float4 w4 = *(const float4*)(Wp + (size_t)cp * C + h * D + d0);
#pragma unroll
                for (int b = 0; b < B; ++b) {
                    const float* vb = vv + (size_t)b * C + d0;
                    aq[q][b] += w4.x * vb[0] + w4.y * vb[1]
                              + w4.z * vb[2] + w4.w * vb[3];
                }
            }
        }
#pragma unroll
        for (int b = 0; b < B; ++b)
            ubuf[(size_t)(b * H + h) * C + cp] =
                __float2bfloat16((aq[0][b] + aq[1][b]) + (aq[2][b] + aq[3][b]));
    }
}

// Kernel C: fused main pass — OCCUPANCY version.
// R4 post-mortem: at 2 waves/SIMD neither VALU (45%) nor LDS (~35%) saturates
// -> latency-bound. Fix: 16 waves/CU (4/SIMD), enabled by
//   (a) bf16-packed LDS again (w+u = 64 KB; halves LDS sweep bytes too;
//       unpack values bit-identical to the f32 staging),
//   (b) 8 rows per wave: 512-thr blocks x 64 rows, grid (64,8)=512 blocks
//       = exactly 2 blocks/CU -> 16 waves/CU,
//   (c) VGPR <= 128 (__launch_bounds__(512,4); prefetch double-buffer
//       dropped -> ~100 regs live).
// Head loop stays ROLLED (R3: code size was the 9x stall). 2-row groups
// keep the weight-sweep amortization. Numerics bit-identical to R4.
__global__ __launch_bounds__(512, 4)
void main_kernel(const float* __restrict__ fea,
                 const __hip_bfloat16* __restrict__ wbuf,
                 const __hip_bfloat16* __restrict__ ubuf,
                 const float* __restrict__ bp,
                 float* __restrict__ out) {
    __shared__ uint32_t w_s[H * C / 2];  // bf16x2 packed, 32 KB
    __shared__ uint32_t u_s[H * C / 2];  // 32 KB
    const int b = blockIdx.y;
    const int tile = blockIdx.x;
    const int tid = threadIdx.x;

    {
        const uint4* wsrc = (const uint4*)(wbuf + (size_t)b * H * C);
        const uint4* usrc = (const uint4*)(ubuf + (size_t)b * H * C);
        uint4* wdst = (uint4*)w_s;
        uint4* udst = (uint4*)u_s;
#pragma unroll
        for (int i = 0; i < H * C / 8 / 512; ++i) {  // 4 iters
            wdst[tid + i * 512] = wsrc[tid + i * 512];
            udst[tid + i * 512] = usrc[tid + i * 512];
        }
    }
    __syncthreads();

    const int lane = tid & 63;
    const int wv = tid >> 6;          // 0..7
    const int row0 = tile * 64 + wv * 8;

    float4 bp4[4];
#pragma unroll
    for (int j = 0; j < 4; ++j) bp4[j] = *(const float4*)(bp + 4 * lane + 256 * j);

    const float* fbase = fea + ((size_t)b * N + row0) * C + 4 * lane;
    float* obase = out + ((size_t)b * N + row0) * C + 4 * lane;

#pragma unroll 1
    for (int g = 0; g < 4; ++g) {
        // Load 2 rows' fea slices (8 x dwordx4), issued together up front.
        float4 f[2][4];
#pragma unroll
        for (int r = 0; r < 2; ++r)
#pragma unroll
            for (int j = 0; j < 4; ++j)
                f[r][j] = *(const float4*)(fbase + (size_t)(2 * g + r) * C + 256 * j);

        float4 acc[2][4];
#pragma unroll
        for (int r = 0; r < 2; ++r)
#pragma unroll
            for (int j = 0; j < 4; ++j) {
                acc[r][j].x = f[r][j].x + bp4[j].x;
                acc[r][j].y = f[r][j].y + bp4[j].y;
                acc[r][j].z = f[r][j].z + bp4[j].z;
                acc[r][j].w = f[r][j].w + bp4[j].w;
            }

#pragma unroll 1
        for (int h = 0; h < H; ++h) {
            const uint32_t* wrow = w_s + h * (C / 2) + 2 * lane;
            float s[2];
            s[0] = 0.f; s[1] = 0.f;
#pragma unroll
            for (int j = 0; j < 4; ++j) {
                uint2 p = *(const uint2*)(wrow + 128 * j);
                float lx = bf_lo(p.x), hx = bf_hi(p.x);
                float ly = bf_lo(p.y), hy = bf_hi(p.y);
#pragma unroll
                for (int r = 0; r < 2; ++r)
                    s[r] += f[r][j].x * lx + f[r][j].y * hx
                          + f[r][j].z * ly + f[r][j].w * hy;
            }
#pragma unroll
            for (int off = 32; off; off >>= 1)
#pragma unroll
                for (int r = 0; r < 2; ++r) s[r] += __shfl_xor(s[r], off, 64);
#pragma unroll
            for (int r = 0; r < 2; ++r)
                s[r] = 1.f / (1.f + __expf(-0.125f * s[r]));

            const uint32_t* urow = u_s + h * (C / 2) + 2 * lane;
#pragma unroll
            for (int j = 0; j < 4; ++j) {
                uint2 p = *(const uint2*)(urow + 128 * j);
                float lx = bf_lo(p.x), hx = bf_hi(p.x);
                float ly = bf_lo(p.y), hy = bf_hi(p.y);
#pragma unroll
                for (int r = 0; r < 2; ++r) {
                    acc[r][j].x += s[r] * lx; acc[r][j].y += s[r] * hx;
                    acc[r][j].z += s[r] * ly; acc[r][j].w += s[r] * hy;
                }
            }
        }

#pragma unroll
        for (int r = 0; r < 2; ++r)
#pragma unroll
            for (int j = 0; j < 4; ++j)
                *(float4*)(obase + (size_t)(2 * g + r) * C + 256 * j) = acc[r][j];
    }
}

extern "C" void kernel_launch(void* const* d_in, const int* in_sizes, int n_in,
                              void* d_out, int out_size, void* d_ws, size_t ws_size,
                              hipStream_t stream) {
    const float* fea = (const float*)d_in[0];
    const float* emb = (const float*)d_in[1];
    const float* Wq  = (const float*)d_in[2];
    const float* Wk  = (const float*)d_in[3];
    const float* Wv  = (const float*)d_in[4];
    const float* Wp  = (const float*)d_in[5];
    const float* bp  = (const float*)d_in[6];
    float* out = (float*)d_out;

    char* ws = (char*)d_ws;
    float* kbuf = (float*)ws;                                  // B*C f32 = 32KB
    float* vbuf = (float*)(ws + 32 * 1024);                    // 32KB
    __hip_bfloat16* wbuf = (__hip_bfloat16*)(ws + 64 * 1024);  // B*H*C bf16 = 256KB
    __hip_bfloat16* ubuf = (__hip_bfloat16*)(ws + 320 * 1024); // 256KB

    hipLaunchKernelGGL(kv_kernel, dim3(2 * C / 4), dim3(256), 0, stream,
                       emb, Wk, Wv, kbuf, vbuf);
    hipLaunchKernelGGL(wu_kernel, dim3(128), dim3(256), 0, stream,
                       Wq, Wp, kbuf, vbuf, wbuf, ubuf);
    hipLaunchKernelGGL(main_kernel, dim3(N / 64, B), dim3(512), 0, stream,
                       fea, wbuf, ubuf, bp, out);
}